// Round 12
// baseline (234.359 us; speedup 1.0000x reference)
//
#include <hip/hip_runtime.h>
#include <hip/hip_bf16.h>

#define B_ 4
#define N_ 1370
#define C_ 1024
#define H_ 16
#define DH_ 64
#define NR_ 1369
#define M_ (B_*N_)   // 5480
#define VTS_ 1408    // padded token stride for transposed V
#define ALS 64       // attn Ks/Vs LDS row stride (swizzled, no pad)
#define PLS 72       // attn Ps LDS row stride (padded, keeps 16B alignment)
#define SVS 200      // qkv v-epilogue LDS tile tok-stride (192+8 pad)

// q pre-scale: (1/sqrt(64)) * log2(e)  -> scores feed v_exp_f32 directly
#define QSCALE 0.1803368801111f

typedef _Float16 f16x8  __attribute__((ext_vector_type(8)));
typedef __bf16   bf16x8 __attribute__((ext_vector_type(8)));
typedef float    f32x4  __attribute__((ext_vector_type(4)));

__device__ __forceinline__ f16x8 ld_frag_h(const unsigned short* p) {
    uint4 u = *(const uint4*)p;
    return __builtin_bit_cast(f16x8, u);
}
__device__ __forceinline__ bf16x8 ld_frag_b(const unsigned short* p) {
    uint4 u = *(const uint4*)p;
    return __builtin_bit_cast(bf16x8, u);
}
__device__ __forceinline__ unsigned short f2h(float f) {
    _Float16 h = (_Float16)f;   // RNE
    return __builtin_bit_cast(unsigned short, h);
}
__device__ __forceinline__ unsigned short f2bf(float f) {
    __hip_bfloat16 h = __float2bfloat16(f);
    return __builtin_bit_cast(unsigned short, h);
}
__device__ __forceinline__ bf16x8 ones_bf() {
    uint4 u = make_uint4(0x3F803F80u, 0x3F803F80u, 0x3F803F80u, 0x3F803F80u);
    return __builtin_bit_cast(bf16x8, u);
}

// async global->LDS, 16B per lane; LDS dst = wave-uniform base + lane*16
__device__ __forceinline__ void load_lds16(const unsigned short* g, unsigned short* l) {
    __builtin_amdgcn_global_load_lds(
        (const __attribute__((address_space(1))) unsigned int*)g,
        (__attribute__((address_space(3))) unsigned int*)l,
        16, 0, 0);
}

// ---------------------------------------------------------------------------
// Fused prep: one launch replaces conv_x + conv_wt(w_qkv) + conv_wt(w_proj),
// plus zero-fill of the vt token pad.
// ---------------------------------------------------------------------------
#define XBLK 5480
#define WQBLK 768   // 48 x 16 tiles of 64x64
#define WPBLK 256   // 16 x 16
#define VTBLK 64    // one block per bh
__global__ __launch_bounds__(256)
void prep_k(const float* __restrict__ x, unsigned short* __restrict__ xo,
            const float* __restrict__ wq, unsigned short* __restrict__ wqt,
            const float* __restrict__ wp, unsigned short* __restrict__ wpt,
            unsigned short* __restrict__ vt)
{
    __shared__ unsigned short Th[64][68];
    int bid = blockIdx.x;
    if (bid < XBLK) {
        const int i = bid * 256 + threadIdx.x;   // total4 = 5480*256 exactly
        float4 v = ((const float4*)x)[i];
        ushort4 h;
        h.x = f2h(v.x); h.y = f2h(v.y); h.z = f2h(v.z); h.w = f2h(v.w);
        ((ushort4*)xo)[i] = h;
        return;
    }
    bid -= XBLK;
    if (bid >= WQBLK + WPBLK) {                  // vt pad zero-fill
        const int bh = bid - (WQBLK + WPBLK);
        unsigned short* base = vt + (size_t)bh * DH_ * VTS_;
        for (int e = threadIdx.x; e < DH_ * (VTS_ - N_); e += 256) {
            const int d = e / (VTS_ - N_), t = e - d * (VTS_ - N_);
            base[(size_t)d * VTS_ + N_ + t] = 0;
        }
        return;
    }
    const float* w; unsigned short* wt; int Ncol, nb;
    if (bid < WQBLK) { w = wq; wt = wqt; Ncol = 3072; nb = 48; }
    else { bid -= WQBLK; w = wp; wt = wpt; Ncol = 1024; nb = 16; }
    const int tid = threadIdx.x, tx = tid & 15, ty = tid >> 4;
    const int n0 = (bid % nb) * 64, k0 = (bid / nb) * 64;
    #pragma unroll
    for (int i = 0; i < 4; ++i) {
        const int k = ty + i * 16;
        float4 v = *(const float4*)&w[(size_t)(k0 + k) * Ncol + n0 + tx * 4];
        Th[k][tx*4+0] = f2h(v.x); Th[k][tx*4+1] = f2h(v.y);
        Th[k][tx*4+2] = f2h(v.z); Th[k][tx*4+3] = f2h(v.w);
    }
    __syncthreads();
    #pragma unroll
    for (int i = 0; i < 4; ++i) {
        const int n = ty + i * 16;
        ushort4 o;
        o.x = Th[tx*4+0][n]; o.y = Th[tx*4+1][n]; o.z = Th[tx*4+2][n]; o.w = Th[tx*4+3][n];
        *(ushort4*)&wt[(size_t)(n0 + n) * 1024 + k0 + tx * 4] = o;
    }
}

// ---------------------------------------------------------------------------
// QKV GEMM (r9/r10 measured-best): 8-wave 2-phase, BM=192, BN=128, BK=64,
// double-buffered LDS (80 KB -> 2 blocks/CU), one barrier per chunk.
// Grid 696 = 8 XCDs x 87 (bijective 1D swizzle).
// Epilogue: q/k fused RoPE; V transposed through the freed staging LDS
// directly to vt[bh][d][VTS_] (r10: removed transpose_v_k AND sped up qkv).
// ---------------------------------------------------------------------------
__global__ __launch_bounds__(512, 4)
void gemm_qkv8(const unsigned short* __restrict__ A, const unsigned short* __restrict__ Bt,
               const float* __restrict__ bias,
               unsigned short* __restrict__ qb, unsigned short* __restrict__ kb,
               unsigned short* __restrict__ vt,
               const float* __restrict__ sinp, const float* __restrict__ cosp)
{
    // 80 KB flat, carved: A_s = [2][192*64] at 0, B_s = [2][128*64] at 24576.
    // v-epilogue reuses [0, 25600) as Sv[128][SVS].
    __shared__ __align__(16) unsigned short SMEM[40960];
    unsigned short* const A_s = SMEM;            // + buf*12288
    unsigned short* const B_s = SMEM + 24576;    // + buf*8192

    const int tid = threadIdx.x;
    const int wave = tid >> 6, lane = tid & 63;
    const int quad = lane >> 4, l16 = lane & 15;

    // bijective XCD swizzle: 696 = 8 XCDs x 87
    const int id  = blockIdx.x;
    const int lid = (id & 7) * 87 + (id >> 3);
    const int mblk = lid / 24, nblk = lid - mblk * 24;
    const int m0 = mblk * 192, n0 = nblk * 128;

    const int mwave = (wave >> 1) * 48;      // 4 M-wave-groups x 48 rows
    const int nwave = (wave & 1) * 64;       // 2 N-wave-groups x 64 cols

    const int srow = lane >> 3;
    const int gseg = (lane & 7) ^ srow;

    f32x4 acc[3][4] = {};

    // stage chunk kc into buffer buf (per-wave: 24 A-rows + 16 B-rows)
    auto stage = [&](int kc, int buf) {
        const int kof = kc * 64;
        #pragma unroll
        for (int i = 0; i < 3; ++i) {
            const int rbase = wave * 24 + i * 8;
            int arow = m0 + rbase + srow;
            if (arow > M_ - 1) arow = M_ - 1;
            load_lds16(A + (size_t)arow * 1024 + kof + gseg * 8,
                       A_s + buf * 12288 + rbase * 64);
        }
        #pragma unroll
        for (int i = 0; i < 2; ++i) {
            const int rbase = wave * 16 + i * 8;
            const int brow = n0 + rbase + srow;
            load_lds16(Bt + (size_t)brow * 1024 + kof + gseg * 8,
                       B_s + buf * 8192 + rbase * 64);
        }
    };

    stage(0, 0);

    for (int kc = 0; kc < 16; ++kc) {
        const int cur = kc & 1;
        // barrier: (a) drains stage(kc) [vmcnt(0) before s_barrier],
        //          (b) all waves done reading buf cur^1 before we overwrite it
        __syncthreads();
        if (kc + 1 < 16) stage(kc + 1, cur ^ 1);

        #pragma unroll
        for (int kh = 0; kh < 2; ++kh) {
            const int soff = (((kh * 4 + quad) ^ (l16 & 7)) << 3);
            f16x8 a[3], b[4];
            #pragma unroll
            for (int t = 0; t < 3; ++t)
                a[t] = ld_frag_h(A_s + cur * 12288 + (mwave + t * 16 + l16) * 64 + soff);
            #pragma unroll
            for (int t = 0; t < 4; ++t)
                b[t] = ld_frag_h(B_s + cur * 8192 + (nwave + t * 16 + l16) * 64 + soff);
            #pragma unroll
            for (int i = 0; i < 3; ++i)
                #pragma unroll
                for (int j = 0; j < 4; ++j)
                    acc[i][j] = __builtin_amdgcn_mfma_f32_16x16x32_f16(a[i], b[j], acc[i][j], 0, 0, 0);
        }
    }

    const int nbase = n0 + nwave;

    if (n0 >= 2048) {
        // ---- V part: transpose through the freed staging LDS ----
        unsigned short* const Sv = SMEM;     // [128][SVS]
        __syncthreads();                     // all waves done with K-loop LDS
        #pragma unroll
        for (int i = 0; i < 3; ++i) {
            #pragma unroll
            for (int r = 0; r < 4; ++r) {
                const int tl = mwave + i * 16 + quad * 4 + r;   // 0..191
                #pragma unroll
                for (int j = 0; j < 4; ++j) {
                    const int c = nwave + j * 16 + l16;          // 0..127
                    Sv[c * SVS + tl] = f2bf(acc[i][j][r] + bias[nbase + j * 16 + l16]);
                }
            }
        }
        __syncthreads();
        // write-out: wave owns 16 c-rows; 64 lanes sweep contiguous toks.
        const int b0 = m0 / N_;
        const int cross = (b0 + 1) * N_ - m0;   // tl >= cross -> batch b0+1
        const int hbase = n0 & 1023;
        for (int cr = 0; cr < 16; ++cr) {
            const int c = wave * 16 + cr;
            const int h = (hbase + c) >> 6;
            const int d = c & 63;
            #pragma unroll
            for (int it = 0; it < 3; ++it) {
                const int tl = it * 64 + lane;
                const int gm = m0 + tl;
                if (gm < M_) {
                    const int b = b0 + (tl >= cross ? 1 : 0);
                    const int tok = gm - b * N_;
                    vt[((size_t)((b * H_ + h) * DH_ + d)) * VTS_ + tok] = Sv[c * SVS + tl];
                }
            }
        }
        return;
    }

    // ---- q/k parts: fused RoPE epilogue (part uniform per block) ----
    const int part = nbase >> 10;            // 0=q, 1=k
    const int h = (nbase & 1023) >> 6;
    #pragma unroll
    for (int i = 0; i < 3; ++i) {
        #pragma unroll
        for (int r = 0; r < 4; ++r) {
            const int gm = m0 + mwave + i * 16 + quad * 4 + r;
            if (gm >= M_) continue;
            const int b = gm / N_;
            const int tok = gm - b * N_;

            float val[4];
            #pragma unroll
            for (int j = 0; j < 4; ++j)
                val[j] = acc[i][j][r] + bias[nbase + j * 16 + l16];

            // fused RoPE (head dim d_j = j*16+l16; pairs (0,2),(1,3))
            if (tok >= 1) {
                const float* sp = sinp + (size_t)(tok - 1) * DH_;
                const float* cp = cosp + (size_t)(tok - 1) * DH_;
                const float s0 = sp[l16],      s1 = sp[16 + l16];
                const float s2 = sp[32 + l16], s3 = sp[48 + l16];
                const float c0 = cp[l16],      c1 = cp[16 + l16];
                const float c2 = cp[32 + l16], c3 = cp[48 + l16];
                const float n0v = fmaf(val[0], c0, -val[2] * s0);
                const float n1v = fmaf(val[1], c1, -val[3] * s1);
                const float n2v = fmaf(val[2], c2,  val[0] * s2);
                const float n3v = fmaf(val[3], c3,  val[1] * s3);
                val[0] = n0v; val[1] = n1v; val[2] = n2v; val[3] = n3v;
            }

            const int bh = b * H_ + h;
            #pragma unroll
            for (int j = 0; j < 4; ++j) {
                const int d = j * 16 + l16;
                if (part == 0) qb[((size_t)bh * N_ + tok) * DH_ + d] = f2h(val[j] * QSCALE);
                else           kb[((size_t)bh * N_ + tok) * DH_ + d] = f2h(val[j]);
            }
        }
    }
}

// ---------------------------------------------------------------------------
// Output projection GEMM (measured-best config, r4): 2-phase double-buffered,
// MT=64, BN=128, BK=64, 256 threads (4 waves 2x2, wave tile 32x64).
// LDS 48 KB -> 3 blocks/CU; grid 688 blocks <= 768 slots -> single round.
// ---------------------------------------------------------------------------
__global__ __launch_bounds__(256)
void gemm_proj2(const unsigned short* __restrict__ A, const unsigned short* __restrict__ Bt,
                const float* __restrict__ bias, float* __restrict__ out)
{
    __shared__ __align__(16) unsigned short A_s[2][64 * 64];
    __shared__ __align__(16) unsigned short B_s[2][128 * 64];

    const int tid = threadIdx.x;
    const int wave = tid >> 6, lane = tid & 63;
    const int quad = lane >> 4, l16 = lane & 15;
    const int m0 = blockIdx.y * 64, n0 = blockIdx.x * 128;
    const int mwave = (wave & 1) * 32, nwave = (wave >> 1) * 64;

    const int srow = lane >> 3;
    const int gseg = (lane & 7) ^ srow;

    f32x4 acc[2][4] = {};

    // stage chunk kc into buffer buf (per-wave: 16 A-rows + 32 B-rows)
    auto stage = [&](int kc, int buf) {
        const int kof = kc * 64;
        #pragma unroll
        for (int i = 0; i < 2; ++i) {
            const int rbase = wave * 16 + i * 8;
            int arow = m0 + rbase + srow;
            if (arow > M_ - 1) arow = M_ - 1;
            load_lds16(A + (size_t)arow * 1024 + kof + gseg * 8, &A_s[buf][rbase * 64]);
        }
        #pragma unroll
        for (int i = 0; i < 4; ++i) {
            const int rbase = wave * 32 + i * 8;
            const int brow = n0 + rbase + srow;
            load_lds16(Bt + (size_t)brow * 1024 + kof + gseg * 8, &B_s[buf][rbase * 64]);
        }
    };

    stage(0, 0);

    for (int kc = 0; kc < 16; ++kc) {
        const int cur = kc & 1;
        __syncthreads();
        if (kc + 1 < 16) stage(kc + 1, cur ^ 1);

        #pragma unroll
        for (int kh = 0; kh < 2; ++kh) {
            const int soff = (((kh * 4 + quad) ^ (l16 & 7)) << 3);
            f16x8 a[2], b[4];
            #pragma unroll
            for (int t = 0; t < 2; ++t)
                a[t] = ld_frag_h(&A_s[cur][(mwave + t * 16 + l16) * 64 + soff]);
            #pragma unroll
            for (int t = 0; t < 4; ++t)
                b[t] = ld_frag_h(&B_s[cur][(nwave + t * 16 + l16) * 64 + soff]);
            #pragma unroll
            for (int i = 0; i < 2; ++i)
                #pragma unroll
                for (int j = 0; j < 4; ++j)
                    acc[i][j] = __builtin_amdgcn_mfma_f32_16x16x32_f16(a[i], b[j], acc[i][j], 0, 0, 0);
        }
    }

    #pragma unroll
    for (int i = 0; i < 2; ++i) {
        #pragma unroll
        for (int r = 0; r < 4; ++r) {
            const int gm = m0 + mwave + i * 16 + quad * 4 + r;
            if (gm >= M_) continue;
            #pragma unroll
            for (int j = 0; j < 4; ++j) {
                const int gn = n0 + nwave + j * 16 + l16;
                out[(size_t)gm * 1024 + gn] = acc[i][j][r] + bias[gn];
            }
        }
    }
}

// ---------------------------------------------------------------------------
// MFMA flash attention, 4-wave x 32 q-rows (LDS-amortization re-tiling of the
// r10 8-wave x 16q kernel; all primitives identical). Rationale: r10 counters
// show no pipe >55% with LDS the most-subscribed shared resource; K/V
// fragment reads (16KB of 20KB per wave-chunk) now amortize over TWO S-tiles
// (24KB per wave-chunk for 2x work = -40% LDS per unit work; per-CU
// chunk-layer 480KB -> 288KB). Same QBLK=128, same 704-block XCD-swizzled
// grid, LDS 50KB -> 3 blocks/CU (12 waves/CU, 3/SIMD).
// QK^T fp16, P/V bf16 (P up to 2^25 needs bf16 range). No running max.
// l via bf16 ones-MFMA. No setprio (m190 regime, r2 measured -15us).
// ---------------------------------------------------------------------------
__global__ __launch_bounds__(256)
void attn_k(const unsigned short* __restrict__ q, const unsigned short* __restrict__ k,
            const unsigned short* __restrict__ vt, unsigned short* __restrict__ out)
{
    __shared__ __align__(16) unsigned short Ks[2][64 * ALS];
    __shared__ __align__(16) unsigned short Vs[2][64 * ALS];
    __shared__ __align__(16) unsigned short Ps[4 * 32 * PLS];

    const int tid  = threadIdx.x;
    const int wave = tid >> 6, lane = tid & 63;   // 4 waves
    const int quad = lane >> 4, l16 = lane & 15;
    const int srow = lane >> 3;
    const int gseg = (lane & 7) ^ srow;

    // bijective XCD swizzle: 704 = 8 XCDs x 88
    const int id  = blockIdx.x;
    const int lid = (id & 7) * 88 + (id >> 3);
    const int bh  = lid / 11;
    const int q0  = (lid - bh * 11) * 128;

    const unsigned short* qp  = q  + (size_t)bh * N_ * DH_;
    const unsigned short* kp  = k  + (size_t)bh * N_ * DH_;
    const unsigned short* vtp = vt + (size_t)bh * DH_ * VTS_;

    f16x8 qf[2][2];
    #pragma unroll
    for (int s = 0; s < 2; ++s) {
        int qrow = q0 + wave * 32 + s * 16 + l16;
        if (qrow > N_ - 1) qrow = N_ - 1;
        qf[s][0] = ld_frag_h(qp + (size_t)qrow * DH_ + quad * 8);
        qf[s][1] = ld_frag_h(qp + (size_t)qrow * DH_ + 32 + quad * 8);
    }

    const bf16x8 onesv = ones_bf();
    f32x4 O[2][4] = {};
    f32x4 L[2] = {};

    unsigned short* Pw = Ps + wave * 32 * PLS;
    const int so0 = ((quad)     ^ (l16 & 7)) << 3;
    const int so1 = ((4 + quad) ^ (l16 & 7)) << 3;

    // stage chunk ch into buffer buf (per-wave slice: 16 K-rows + 16 Vt-rows)
    auto stage = [&](int ch, int buf) {
        const int k0 = ch * 64;
        #pragma unroll
        for (int i = 0; i < 2; ++i) {
            const int rbase = wave * 16 + i * 8;
            int krow = k0 + rbase + srow;
            if (krow > N_ - 1) krow = N_ - 1;
            load_lds16(kp + (size_t)krow * DH_ + gseg * 8, &Ks[buf][rbase * ALS]);
            load_lds16(vtp + (size_t)(rbase + srow) * VTS_ + k0 + gseg * 8, &Vs[buf][rbase * ALS]);
        }
    };

    stage(0, 0);

    for (int ch = 0; ch < 22; ++ch) {
        const int k0 = ch * 64;
        const int cur = ch & 1;
        __syncthreads();
        if (ch + 1 < 22) stage(ch + 1, 1 - cur);

        f16x8 kf[4][2];
        #pragma unroll
        for (int t = 0; t < 4; ++t) {
            kf[t][0] = ld_frag_h(&Ks[cur][(t * 16 + l16) * ALS + so0]);
            kf[t][1] = ld_frag_h(&Ks[cur][(t * 16 + l16) * ALS + so1]);
        }
        f32x4 S[2][4];
        #pragma unroll
        for (int s = 0; s < 2; ++s) {
            #pragma unroll
            for (int t = 0; t < 4; ++t) {
                f32x4 z = {};
                z = __builtin_amdgcn_mfma_f32_16x16x32_f16(qf[s][0], kf[t][0], z, 0, 0, 0);
                z = __builtin_amdgcn_mfma_f32_16x16x32_f16(qf[s][1], kf[t][1], z, 0, 0, 0);
                S[s][t] = z;
            }
        }
        if (k0 + 64 > N_) {
            #pragma unroll
            for (int t = 0; t < 4; ++t) {
                if (k0 + t * 16 + l16 >= N_) {
                    #pragma unroll
                    for (int s = 0; s < 2; ++s) {
                        S[s][t][0] = -1e30f; S[s][t][1] = -1e30f;
                        S[s][t][2] = -1e30f; S[s][t][3] = -1e30f;
                    }
                }
            }
        }

        #pragma unroll
        for (int s = 0; s < 2; ++s) {
            #pragma unroll
            for (int t = 0; t < 4; ++t) {
                #pragma unroll
                for (int r = 0; r < 4; ++r) {
                    const float p = __builtin_amdgcn_exp2f(S[s][t][r]);
                    Pw[(s * 16 + quad * 4 + r) * PLS + t * 16 + l16] = f2bf(p);
                }
            }
        }
        __builtin_amdgcn_wave_barrier();   // DS write->read order (intra-wave)

        bf16x8 pf[2][2];
        #pragma unroll
        for (int s = 0; s < 2; ++s) {
            pf[s][0] = ld_frag_b(&Pw[(s * 16 + l16) * PLS + quad * 8]);
            pf[s][1] = ld_frag_b(&Pw[(s * 16 + l16) * PLS + 32 + quad * 8]);
        }
        bf16x8 vf[4][2];
        #pragma unroll
        for (int dt = 0; dt < 4; ++dt) {
            vf[dt][0] = ld_frag_b(&Vs[cur][(dt * 16 + l16) * ALS + so0]);
            vf[dt][1] = ld_frag_b(&Vs[cur][(dt * 16 + l16) * ALS + so1]);
        }
        #pragma unroll
        for (int s = 0; s < 2; ++s) {
            L[s] = __builtin_amdgcn_mfma_f32_16x16x32_bf16(pf[s][0], onesv, L[s], 0, 0, 0);
            L[s] = __builtin_amdgcn_mfma_f32_16x16x32_bf16(pf[s][1], onesv, L[s], 0, 0, 0);
            #pragma unroll
            for (int dt = 0; dt < 4; ++dt) {
                O[s][dt] = __builtin_amdgcn_mfma_f32_16x16x32_bf16(pf[s][0], vf[dt][0], O[s][dt], 0, 0, 0);
                O[s][dt] = __builtin_amdgcn_mfma_f32_16x16x32_bf16(pf[s][1], vf[dt][1], O[s][dt], 0, 0, 0);
            }
        }
    }

    const int b = bh >> 4, h = bh & 15;
    #pragma unroll
    for (int s = 0; s < 2; ++s) {
        #pragma unroll
        for (int r = 0; r < 4; ++r) {
            const int qi = q0 + wave * 32 + s * 16 + quad * 4 + r;
            if (qi < N_) {
                const float inv = 1.0f / L[s][r];
                unsigned short* op = out + ((size_t)(b * N_ + qi)) * C_ + h * DH_ + l16;
                #pragma unroll
                for (int dt = 0; dt < 4; ++dt) op[dt * 16] = f2h(O[s][dt][r] * inv);
            }
        }
    }
}

// ---------------------------------------------------------------------------
extern "C" void kernel_launch(void* const* d_in, const int* in_sizes, int n_in,
                              void* d_out, int out_size, void* d_ws, size_t ws_size,
                              hipStream_t stream) {
    const float* x      = (const float*)d_in[0];
    const float* sinp   = (const float*)d_in[1];
    const float* cosp   = (const float*)d_in[2];
    const float* w_qkv  = (const float*)d_in[3];
    const float* b_qkv  = (const float*)d_in[4];
    const float* w_proj = (const float*)d_in[5];
    const float* b_proj = (const float*)d_in[6];
    float* out = (float*)d_out;

    unsigned short* p = (unsigned short*)d_ws;
    const size_t xsz  = (size_t)M_ * C_;
    const size_t wqsz = (size_t)3 * C_ * C_;
    const size_t wpsz = (size_t)C_ * C_;
    const size_t hsz  = (size_t)B_ * H_ * N_ * DH_;
    const size_t vtsz = (size_t)B_ * H_ * DH_ * VTS_;
    unsigned short* x_h   = p;            p += xsz;
    unsigned short* wq_t  = p;            p += wqsz;
    unsigned short* wp_t  = p;            p += wpsz;
    unsigned short* q     = p;            p += hsz;
    unsigned short* k     = p;            p += hsz;
    unsigned short* vt    = p;            p += vtsz;
    unsigned short* attnb = p;            p += xsz;

    // fused prep: x convert + both weight transposes + vt pad zero-fill
    prep_k<<<dim3(XBLK + WQBLK + WPBLK + VTBLK), 256, 0, stream>>>(
        x, x_h, w_qkv, wq_t, w_proj, wp_t, vt);

    // QKV projection: 8-wave 2-phase GEMM (BM=192), fused RoPE epilogue,
    // V written TRANSPOSED directly (LDS-reuse transpose in epilogue).
    gemm_qkv8<<<dim3(696), 512, 0, stream>>>(
        x_h, wq_t, b_qkv, q, k, vt, sinp, cosp);

    // attention: 4-wave x 32q blocks, 704 blocks (11 q-tiles x 64 bh),
    // XCD-swizzled
    attn_k<<<dim3(11 * B_ * H_), 256, 0, stream>>>(q, k, vt, attnb);

    // output projection: 2-phase MT=64 tile -> 688 blocks (3 blocks/CU,
    // single round)
    gemm_proj2<<<dim3(C_ / 128, (M_ + 63) / 64), 256, 0, stream>>>(
        attnb, wp_t, b_proj, out);
}

// Round 13
// 217.093 us; speedup vs baseline: 1.0795x; 1.0795x over previous
//
#include <hip/hip_runtime.h>
#include <hip/hip_bf16.h>

#define B_ 4
#define N_ 1370
#define C_ 1024
#define H_ 16
#define DH_ 64
#define NR_ 1369
#define M_ (B_*N_)   // 5480
#define VTS_ 1408    // padded token stride for transposed V
#define ALS 64       // attn Ks/Vs LDS row stride (swizzled, no pad)
#define PLS 72       // attn Ps LDS row stride (padded, keeps 16B alignment)
#define SVS 200      // qkv v-epilogue LDS tile tok-stride (192+8 pad)

// q pre-scale: (1/sqrt(64)) * log2(e)  -> scores feed v_exp_f32 directly
#define QSCALE 0.1803368801111f

typedef _Float16 f16x8  __attribute__((ext_vector_type(8)));
typedef __bf16   bf16x8 __attribute__((ext_vector_type(8)));
typedef float    f32x4  __attribute__((ext_vector_type(4)));

__device__ __forceinline__ f16x8 ld_frag_h(const unsigned short* p) {
    uint4 u = *(const uint4*)p;
    return __builtin_bit_cast(f16x8, u);
}
__device__ __forceinline__ bf16x8 ld_frag_b(const unsigned short* p) {
    uint4 u = *(const uint4*)p;
    return __builtin_bit_cast(bf16x8, u);
}
__device__ __forceinline__ unsigned short f2h(float f) {
    _Float16 h = (_Float16)f;   // RNE
    return __builtin_bit_cast(unsigned short, h);
}
__device__ __forceinline__ unsigned short f2bf(float f) {
    __hip_bfloat16 h = __float2bfloat16(f);
    return __builtin_bit_cast(unsigned short, h);
}
__device__ __forceinline__ bf16x8 ones_bf() {
    uint4 u = make_uint4(0x3F803F80u, 0x3F803F80u, 0x3F803F80u, 0x3F803F80u);
    return __builtin_bit_cast(bf16x8, u);
}

// async global->LDS, 16B per lane; LDS dst = wave-uniform base + lane*16
__device__ __forceinline__ void load_lds16(const unsigned short* g, unsigned short* l) {
    __builtin_amdgcn_global_load_lds(
        (const __attribute__((address_space(1))) unsigned int*)g,
        (__attribute__((address_space(3))) unsigned int*)l,
        16, 0, 0);
}

// ---------------------------------------------------------------------------
// Fused prep: one launch replaces conv_x + conv_wt(w_qkv) + conv_wt(w_proj),
// plus zero-fill of the vt token pad.
// ---------------------------------------------------------------------------
#define XBLK 5480
#define WQBLK 768   // 48 x 16 tiles of 64x64
#define WPBLK 256   // 16 x 16
#define VTBLK 64    // one block per bh
__global__ __launch_bounds__(256)
void prep_k(const float* __restrict__ x, unsigned short* __restrict__ xo,
            const float* __restrict__ wq, unsigned short* __restrict__ wqt,
            const float* __restrict__ wp, unsigned short* __restrict__ wpt,
            unsigned short* __restrict__ vt)
{
    __shared__ unsigned short Th[64][68];
    int bid = blockIdx.x;
    if (bid < XBLK) {
        const int i = bid * 256 + threadIdx.x;   // total4 = 5480*256 exactly
        float4 v = ((const float4*)x)[i];
        ushort4 h;
        h.x = f2h(v.x); h.y = f2h(v.y); h.z = f2h(v.z); h.w = f2h(v.w);
        ((ushort4*)xo)[i] = h;
        return;
    }
    bid -= XBLK;
    if (bid >= WQBLK + WPBLK) {                  // vt pad zero-fill
        const int bh = bid - (WQBLK + WPBLK);
        unsigned short* base = vt + (size_t)bh * DH_ * VTS_;
        for (int e = threadIdx.x; e < DH_ * (VTS_ - N_); e += 256) {
            const int d = e / (VTS_ - N_), t = e - d * (VTS_ - N_);
            base[(size_t)d * VTS_ + N_ + t] = 0;
        }
        return;
    }
    const float* w; unsigned short* wt; int Ncol, nb;
    if (bid < WQBLK) { w = wq; wt = wqt; Ncol = 3072; nb = 48; }
    else { bid -= WQBLK; w = wp; wt = wpt; Ncol = 1024; nb = 16; }
    const int tid = threadIdx.x, tx = tid & 15, ty = tid >> 4;
    const int n0 = (bid % nb) * 64, k0 = (bid / nb) * 64;
    #pragma unroll
    for (int i = 0; i < 4; ++i) {
        const int k = ty + i * 16;
        float4 v = *(const float4*)&w[(size_t)(k0 + k) * Ncol + n0 + tx * 4];
        Th[k][tx*4+0] = f2h(v.x); Th[k][tx*4+1] = f2h(v.y);
        Th[k][tx*4+2] = f2h(v.z); Th[k][tx*4+3] = f2h(v.w);
    }
    __syncthreads();
    #pragma unroll
    for (int i = 0; i < 4; ++i) {
        const int n = ty + i * 16;
        ushort4 o;
        o.x = Th[tx*4+0][n]; o.y = Th[tx*4+1][n]; o.z = Th[tx*4+2][n]; o.w = Th[tx*4+3][n];
        *(ushort4*)&wt[(size_t)(n0 + n) * 1024 + k0 + tx * 4] = o;
    }
}

// ---------------------------------------------------------------------------
// QKV GEMM (r9/r10 measured-best): 8-wave 2-phase, BM=192, BN=128, BK=64,
// double-buffered LDS (80 KB -> 2 blocks/CU), one barrier per chunk.
// Grid 696 = 8 XCDs x 87 (bijective 1D swizzle).
// Epilogue: q/k fused RoPE; V transposed through the freed staging LDS
// directly to vt[bh][d][VTS_] (r10: removed transpose_v_k AND sped up qkv).
// ---------------------------------------------------------------------------
__global__ __launch_bounds__(512, 4)
void gemm_qkv8(const unsigned short* __restrict__ A, const unsigned short* __restrict__ Bt,
               const float* __restrict__ bias,
               unsigned short* __restrict__ qb, unsigned short* __restrict__ kb,
               unsigned short* __restrict__ vt,
               const float* __restrict__ sinp, const float* __restrict__ cosp)
{
    // 80 KB flat, carved: A_s = [2][192*64] at 0, B_s = [2][128*64] at 24576.
    // v-epilogue reuses [0, 25600) as Sv[128][SVS].
    __shared__ __align__(16) unsigned short SMEM[40960];
    unsigned short* const A_s = SMEM;            // + buf*12288
    unsigned short* const B_s = SMEM + 24576;    // + buf*8192

    const int tid = threadIdx.x;
    const int wave = tid >> 6, lane = tid & 63;
    const int quad = lane >> 4, l16 = lane & 15;

    // bijective XCD swizzle: 696 = 8 XCDs x 87
    const int id  = blockIdx.x;
    const int lid = (id & 7) * 87 + (id >> 3);
    const int mblk = lid / 24, nblk = lid - mblk * 24;
    const int m0 = mblk * 192, n0 = nblk * 128;

    const int mwave = (wave >> 1) * 48;      // 4 M-wave-groups x 48 rows
    const int nwave = (wave & 1) * 64;       // 2 N-wave-groups x 64 cols

    const int srow = lane >> 3;
    const int gseg = (lane & 7) ^ srow;

    f32x4 acc[3][4] = {};

    // stage chunk kc into buffer buf (per-wave: 24 A-rows + 16 B-rows)
    auto stage = [&](int kc, int buf) {
        const int kof = kc * 64;
        #pragma unroll
        for (int i = 0; i < 3; ++i) {
            const int rbase = wave * 24 + i * 8;
            int arow = m0 + rbase + srow;
            if (arow > M_ - 1) arow = M_ - 1;
            load_lds16(A + (size_t)arow * 1024 + kof + gseg * 8,
                       A_s + buf * 12288 + rbase * 64);
        }
        #pragma unroll
        for (int i = 0; i < 2; ++i) {
            const int rbase = wave * 16 + i * 8;
            const int brow = n0 + rbase + srow;
            load_lds16(Bt + (size_t)brow * 1024 + kof + gseg * 8,
                       B_s + buf * 8192 + rbase * 64);
        }
    };

    stage(0, 0);

    for (int kc = 0; kc < 16; ++kc) {
        const int cur = kc & 1;
        // barrier: (a) drains stage(kc) [vmcnt(0) before s_barrier],
        //          (b) all waves done reading buf cur^1 before we overwrite it
        __syncthreads();
        if (kc + 1 < 16) stage(kc + 1, cur ^ 1);

        #pragma unroll
        for (int kh = 0; kh < 2; ++kh) {
            const int soff = (((kh * 4 + quad) ^ (l16 & 7)) << 3);
            f16x8 a[3], b[4];
            #pragma unroll
            for (int t = 0; t < 3; ++t)
                a[t] = ld_frag_h(A_s + cur * 12288 + (mwave + t * 16 + l16) * 64 + soff);
            #pragma unroll
            for (int t = 0; t < 4; ++t)
                b[t] = ld_frag_h(B_s + cur * 8192 + (nwave + t * 16 + l16) * 64 + soff);
            #pragma unroll
            for (int i = 0; i < 3; ++i)
                #pragma unroll
                for (int j = 0; j < 4; ++j)
                    acc[i][j] = __builtin_amdgcn_mfma_f32_16x16x32_f16(a[i], b[j], acc[i][j], 0, 0, 0);
        }
    }

    const int nbase = n0 + nwave;

    if (n0 >= 2048) {
        // ---- V part: transpose through the freed staging LDS ----
        unsigned short* const Sv = SMEM;     // [128][SVS]
        __syncthreads();                     // all waves done with K-loop LDS
        #pragma unroll
        for (int i = 0; i < 3; ++i) {
            #pragma unroll
            for (int r = 0; r < 4; ++r) {
                const int tl = mwave + i * 16 + quad * 4 + r;   // 0..191
                #pragma unroll
                for (int j = 0; j < 4; ++j) {
                    const int c = nwave + j * 16 + l16;          // 0..127
                    Sv[c * SVS + tl] = f2bf(acc[i][j][r] + bias[nbase + j * 16 + l16]);
                }
            }
        }
        __syncthreads();
        // write-out: wave owns 16 c-rows; 64 lanes sweep contiguous toks.
        const int b0 = m0 / N_;
        const int cross = (b0 + 1) * N_ - m0;   // tl >= cross -> batch b0+1
        const int hbase = n0 & 1023;
        for (int cr = 0; cr < 16; ++cr) {
            const int c = wave * 16 + cr;
            const int h = (hbase + c) >> 6;
            const int d = c & 63;
            #pragma unroll
            for (int it = 0; it < 3; ++it) {
                const int tl = it * 64 + lane;
                const int gm = m0 + tl;
                if (gm < M_) {
                    const int b = b0 + (tl >= cross ? 1 : 0);
                    const int tok = gm - b * N_;
                    vt[((size_t)((b * H_ + h) * DH_ + d)) * VTS_ + tok] = Sv[c * SVS + tl];
                }
            }
        }
        return;
    }

    // ---- q/k parts: fused RoPE epilogue (part uniform per block) ----
    const int part = nbase >> 10;            // 0=q, 1=k
    const int h = (nbase & 1023) >> 6;
    #pragma unroll
    for (int i = 0; i < 3; ++i) {
        #pragma unroll
        for (int r = 0; r < 4; ++r) {
            const int gm = m0 + mwave + i * 16 + quad * 4 + r;
            if (gm >= M_) continue;
            const int b = gm / N_;
            const int tok = gm - b * N_;

            float val[4];
            #pragma unroll
            for (int j = 0; j < 4; ++j)
                val[j] = acc[i][j][r] + bias[nbase + j * 16 + l16];

            // fused RoPE (head dim d_j = j*16+l16; pairs (0,2),(1,3))
            if (tok >= 1) {
                const float* sp = sinp + (size_t)(tok - 1) * DH_;
                const float* cp = cosp + (size_t)(tok - 1) * DH_;
                const float s0 = sp[l16],      s1 = sp[16 + l16];
                const float s2 = sp[32 + l16], s3 = sp[48 + l16];
                const float c0 = cp[l16],      c1 = cp[16 + l16];
                const float c2 = cp[32 + l16], c3 = cp[48 + l16];
                const float n0v = fmaf(val[0], c0, -val[2] * s0);
                const float n1v = fmaf(val[1], c1, -val[3] * s1);
                const float n2v = fmaf(val[2], c2,  val[0] * s2);
                const float n3v = fmaf(val[3], c3,  val[1] * s3);
                val[0] = n0v; val[1] = n1v; val[2] = n2v; val[3] = n3v;
            }

            const int bh = b * H_ + h;
            #pragma unroll
            for (int j = 0; j < 4; ++j) {
                const int d = j * 16 + l16;
                if (part == 0) qb[((size_t)bh * N_ + tok) * DH_ + d] = f2h(val[j] * QSCALE);
                else           kb[((size_t)bh * N_ + tok) * DH_ + d] = f2h(val[j]);
            }
        }
    }
}

// ---------------------------------------------------------------------------
// Output projection GEMM (measured-best config, r4): 2-phase double-buffered,
// MT=64, BN=128, BK=64, 256 threads (4 waves 2x2, wave tile 32x64).
// LDS 48 KB -> 3 blocks/CU; grid 688 blocks <= 768 slots -> single round.
// ---------------------------------------------------------------------------
__global__ __launch_bounds__(256)
void gemm_proj2(const unsigned short* __restrict__ A, const unsigned short* __restrict__ Bt,
                const float* __restrict__ bias, float* __restrict__ out)
{
    __shared__ __align__(16) unsigned short A_s[2][64 * 64];
    __shared__ __align__(16) unsigned short B_s[2][128 * 64];

    const int tid = threadIdx.x;
    const int wave = tid >> 6, lane = tid & 63;
    const int quad = lane >> 4, l16 = lane & 15;
    const int m0 = blockIdx.y * 64, n0 = blockIdx.x * 128;
    const int mwave = (wave & 1) * 32, nwave = (wave >> 1) * 64;

    const int srow = lane >> 3;
    const int gseg = (lane & 7) ^ srow;

    f32x4 acc[2][4] = {};

    // stage chunk kc into buffer buf (per-wave: 16 A-rows + 32 B-rows)
    auto stage = [&](int kc, int buf) {
        const int kof = kc * 64;
        #pragma unroll
        for (int i = 0; i < 2; ++i) {
            const int rbase = wave * 16 + i * 8;
            int arow = m0 + rbase + srow;
            if (arow > M_ - 1) arow = M_ - 1;
            load_lds16(A + (size_t)arow * 1024 + kof + gseg * 8, &A_s[buf][rbase * 64]);
        }
        #pragma unroll
        for (int i = 0; i < 4; ++i) {
            const int rbase = wave * 32 + i * 8;
            const int brow = n0 + rbase + srow;
            load_lds16(Bt + (size_t)brow * 1024 + kof + gseg * 8, &B_s[buf][rbase * 64]);
        }
    };

    stage(0, 0);

    for (int kc = 0; kc < 16; ++kc) {
        const int cur = kc & 1;
        __syncthreads();
        if (kc + 1 < 16) stage(kc + 1, cur ^ 1);

        #pragma unroll
        for (int kh = 0; kh < 2; ++kh) {
            const int soff = (((kh * 4 + quad) ^ (l16 & 7)) << 3);
            f16x8 a[2], b[4];
            #pragma unroll
            for (int t = 0; t < 2; ++t)
                a[t] = ld_frag_h(&A_s[cur][(mwave + t * 16 + l16) * 64 + soff]);
            #pragma unroll
            for (int t = 0; t < 4; ++t)
                b[t] = ld_frag_h(&B_s[cur][(nwave + t * 16 + l16) * 64 + soff]);
            #pragma unroll
            for (int i = 0; i < 2; ++i)
                #pragma unroll
                for (int j = 0; j < 4; ++j)
                    acc[i][j] = __builtin_amdgcn_mfma_f32_16x16x32_f16(a[i], b[j], acc[i][j], 0, 0, 0);
        }
    }

    #pragma unroll
    for (int i = 0; i < 2; ++i) {
        #pragma unroll
        for (int r = 0; r < 4; ++r) {
            const int gm = m0 + mwave + i * 16 + quad * 4 + r;
            if (gm >= M_) continue;
            #pragma unroll
            for (int j = 0; j < 4; ++j) {
                const int gn = n0 + nwave + j * 16 + l16;
                out[(size_t)gm * 1024 + gn] = acc[i][j][r] + bias[gn];
            }
        }
    }
}

// ---------------------------------------------------------------------------
// MFMA flash attention, 8-wave x 16 q-rows (r10 measured-best; r12's 4-wave
// x 32q re-tiling REGRESSED 59.5 -> 66us: VALUBusy 30->40%, Occupancy
// 41->21.5% -- the kernel is latency-chain-bound and wave-count (TLP) is
// the protective resource, not LDS bandwidth). QK^T fp16, P/V bf16 (P up
// to 2^25 needs bf16 range). Double-buffered K/V, one barrier per chunk.
// No running max. l via bf16 ones-MFMA. No setprio (r2: -15us, m190
// regime). LDS 50KB -> 3 blocks/CU (24 waves/CU). Bijective XCD swizzle:
// 704 blocks = 8 XCDs x 88 (FETCH 95 -> 16.6MB, r3).
// ---------------------------------------------------------------------------
__global__ __launch_bounds__(512, 6)
void attn_k(const unsigned short* __restrict__ q, const unsigned short* __restrict__ k,
            const unsigned short* __restrict__ vt, unsigned short* __restrict__ out)
{
    __shared__ __align__(16) unsigned short Ks[2][64 * ALS];
    __shared__ __align__(16) unsigned short Vs[2][64 * ALS];
    __shared__ __align__(16) unsigned short Ps[8 * 16 * PLS];

    const int tid  = threadIdx.x;
    const int wave = tid >> 6, lane = tid & 63;   // 8 waves
    const int quad = lane >> 4, l16 = lane & 15;
    const int srow = lane >> 3;
    const int gseg = (lane & 7) ^ srow;

    const int id  = blockIdx.x;
    const int lid = (id & 7) * 88 + (id >> 3);
    const int bh  = lid / 11;
    const int q0  = (lid - bh * 11) * 128;

    const unsigned short* qp  = q  + (size_t)bh * N_ * DH_;
    const unsigned short* kp  = k  + (size_t)bh * N_ * DH_;
    const unsigned short* vtp = vt + (size_t)bh * DH_ * VTS_;

    f16x8 qf[2];
    {
        int qrow = q0 + wave * 16 + l16;
        if (qrow > N_ - 1) qrow = N_ - 1;
        qf[0] = ld_frag_h(qp + (size_t)qrow * DH_ + quad * 8);
        qf[1] = ld_frag_h(qp + (size_t)qrow * DH_ + 32 + quad * 8);
    }

    const bf16x8 onesv = ones_bf();
    f32x4 O[4] = {};
    f32x4 L = {};

    unsigned short* Pw = Ps + wave * 16 * PLS;
    const int so0 = ((quad)     ^ (l16 & 7)) << 3;
    const int so1 = ((4 + quad) ^ (l16 & 7)) << 3;

    // stage chunk ch into buffer buf (per-wave slice: 8 K-rows + 8 Vt-rows)
    auto stage = [&](int ch, int buf) {
        const int k0 = ch * 64;
        const int rbase = wave * 8;
        int krow = k0 + rbase + srow;
        if (krow > N_ - 1) krow = N_ - 1;
        load_lds16(kp + (size_t)krow * DH_ + gseg * 8, &Ks[buf][rbase * ALS]);
        load_lds16(vtp + (size_t)(rbase + srow) * VTS_ + k0 + gseg * 8, &Vs[buf][rbase * ALS]);
    };

    stage(0, 0);

    for (int ch = 0; ch < 22; ++ch) {
        const int k0 = ch * 64;
        const int cur = ch & 1;
        __syncthreads();
        if (ch + 1 < 22) stage(ch + 1, 1 - cur);

        f16x8 kf[4][2];
        #pragma unroll
        for (int t = 0; t < 4; ++t) {
            kf[t][0] = ld_frag_h(&Ks[cur][(t * 16 + l16) * ALS + so0]);
            kf[t][1] = ld_frag_h(&Ks[cur][(t * 16 + l16) * ALS + so1]);
        }
        f32x4 S[4];
        #pragma unroll
        for (int t = 0; t < 4; ++t) {
            f32x4 z = {};
            z = __builtin_amdgcn_mfma_f32_16x16x32_f16(qf[0], kf[t][0], z, 0, 0, 0);
            z = __builtin_amdgcn_mfma_f32_16x16x32_f16(qf[1], kf[t][1], z, 0, 0, 0);
            S[t] = z;
        }
        if (k0 + 64 > N_) {
            #pragma unroll
            for (int t = 0; t < 4; ++t) {
                if (k0 + t * 16 + l16 >= N_) {
                    S[t][0] = -1e30f; S[t][1] = -1e30f;
                    S[t][2] = -1e30f; S[t][3] = -1e30f;
                }
            }
        }

        #pragma unroll
        for (int t = 0; t < 4; ++t) {
            #pragma unroll
            for (int r = 0; r < 4; ++r) {
                const float p = __builtin_amdgcn_exp2f(S[t][r]);
                Pw[(quad * 4 + r) * PLS + t * 16 + l16] = f2bf(p);
            }
        }
        __builtin_amdgcn_wave_barrier();   // DS write->read order (intra-wave)

        bf16x8 pf[2];
        pf[0] = ld_frag_b(&Pw[l16 * PLS + quad * 8]);
        pf[1] = ld_frag_b(&Pw[l16 * PLS + 32 + quad * 8]);

        bf16x8 vf[4][2];
        #pragma unroll
        for (int dt = 0; dt < 4; ++dt) {
            vf[dt][0] = ld_frag_b(&Vs[cur][(dt * 16 + l16) * ALS + so0]);
            vf[dt][1] = ld_frag_b(&Vs[cur][(dt * 16 + l16) * ALS + so1]);
        }
        L = __builtin_amdgcn_mfma_f32_16x16x32_bf16(pf[0], onesv, L, 0, 0, 0);
        L = __builtin_amdgcn_mfma_f32_16x16x32_bf16(pf[1], onesv, L, 0, 0, 0);
        #pragma unroll
        for (int dt = 0; dt < 4; ++dt) {
            O[dt] = __builtin_amdgcn_mfma_f32_16x16x32_bf16(pf[0], vf[dt][0], O[dt], 0, 0, 0);
            O[dt] = __builtin_amdgcn_mfma_f32_16x16x32_bf16(pf[1], vf[dt][1], O[dt], 0, 0, 0);
        }
    }

    const int b = bh >> 4, h = bh & 15;
    #pragma unroll
    for (int r = 0; r < 4; ++r) {
        const int qi = q0 + wave * 16 + quad * 4 + r;
        if (qi < N_) {
            const float inv = 1.0f / L[r];
            unsigned short* op = out + ((size_t)(b * N_ + qi)) * C_ + h * DH_ + l16;
            #pragma unroll
            for (int dt = 0; dt < 4; ++dt) op[dt * 16] = f2h(O[dt][r] * inv);
        }
    }
}

// ---------------------------------------------------------------------------
extern "C" void kernel_launch(void* const* d_in, const int* in_sizes, int n_in,
                              void* d_out, int out_size, void* d_ws, size_t ws_size,
                              hipStream_t stream) {
    const float* x      = (const float*)d_in[0];
    const float* sinp   = (const float*)d_in[1];
    const float* cosp   = (const float*)d_in[2];
    const float* w_qkv  = (const float*)d_in[3];
    const float* b_qkv  = (const float*)d_in[4];
    const float* w_proj = (const float*)d_in[5];
    const float* b_proj = (const float*)d_in[6];
    float* out = (float*)d_out;

    unsigned short* p = (unsigned short*)d_ws;
    const size_t xsz  = (size_t)M_ * C_;
    const size_t wqsz = (size_t)3 * C_ * C_;
    const size_t wpsz = (size_t)C_ * C_;
    const size_t hsz  = (size_t)B_ * H_ * N_ * DH_;
    const size_t vtsz = (size_t)B_ * H_ * DH_ * VTS_;
    unsigned short* x_h   = p;            p += xsz;
    unsigned short* wq_t  = p;            p += wqsz;
    unsigned short* wp_t  = p;            p += wpsz;
    unsigned short* q     = p;            p += hsz;
    unsigned short* k     = p;            p += hsz;
    unsigned short* vt    = p;            p += vtsz;
    unsigned short* attnb = p;            p += xsz;

    // fused prep: x convert + both weight transposes + vt pad zero-fill
    prep_k<<<dim3(XBLK + WQBLK + WPBLK + VTBLK), 256, 0, stream>>>(
        x, x_h, w_qkv, wq_t, w_proj, wp_t, vt);

    // QKV projection: 8-wave 2-phase GEMM (BM=192), fused RoPE epilogue,
    // V written TRANSPOSED directly (LDS-reuse transpose in epilogue).
    gemm_qkv8<<<dim3(696), 512, 0, stream>>>(
        x_h, wq_t, b_qkv, q, k, vt, sinp, cosp);

    // attention: 8-wave x 16q blocks, 704 blocks (11 q-tiles x 64 bh),
    // XCD-swizzled
    attn_k<<<dim3(11 * B_ * H_), 512, 0, stream>>>(q, k, vt, attnb);

    // output projection: 2-phase MT=64 tile -> 688 blocks (3 blocks/CU,
    // single round)
    gemm_proj2<<<dim3(C_ / 128, (M_ + 63) / 64), 256, 0, stream>>>(
        attnb, wp_t, b_proj, out);
}